// Round 9
// baseline (315.286 us; speedup 1.0000x reference)
//
#include <hip/hip_runtime.h>
#include <hip/hip_bf16.h>

#define NN   50000
#define NE   160000
#define DDIM 512
#define MPAD 50048          // 391 * 128
#define NB_SCAN 196         // ceil(NN/256)

typedef __attribute__((ext_vector_type(8))) short  short8;
typedef __attribute__((ext_vector_type(8))) unsigned short ushort8;
typedef __attribute__((ext_vector_type(4))) float  f32x4;

__device__ __forceinline__ unsigned short f2bf(float f) {
  union { float f; unsigned u; } v; v.f = f;
  unsigned u = v.u;
  unsigned r = (u + 0x7FFFu + ((u >> 16) & 1u)) >> 16;   // RNE
  return (unsigned short)r;
}
__device__ __forceinline__ float bf2f(unsigned short s) {
  union { unsigned u; float f; } v; v.u = ((unsigned)s) << 16;
  return v.f;
}
__device__ __forceinline__ void unpack8(uint4 v, float* t) {
  t[0] = bf2f(v.x & 0xffff); t[1] = bf2f(v.x >> 16);
  t[2] = bf2f(v.y & 0xffff); t[3] = bf2f(v.y >> 16);
  t[4] = bf2f(v.z & 0xffff); t[5] = bf2f(v.z >> 16);
  t[6] = bf2f(v.w & 0xffff); t[7] = bf2f(v.w >> 16);
}
__device__ __forceinline__ void gload_lds16(const void* g, void* l) {
  __builtin_amdgcn_global_load_lds(
      (const __attribute__((address_space(1))) unsigned int*)g,
      (__attribute__((address_space(3))) unsigned int*)l, 16, 0, 0);
}

// ---------------- fused prep: cvt_x + cvt_w (both) + cnt zero ----------------
__global__ __launch_bounds__(256) void k_prep(
    const float* __restrict__ x, const float* __restrict__ W1,
    const float* __restrict__ W2, unsigned short* __restrict__ xb,
    unsigned short* __restrict__ Wt1, unsigned short* __restrict__ Wt2,
    int* __restrict__ cnt)
{
  int stride = gridDim.x * 256;
  int g0 = blockIdx.x * 256 + threadIdx.x;
  // x f32 -> bf16 (padded rows zeroed), 8 elems per iteration
  for (size_t t = g0; t < (size_t)MPAD * 64; t += stride) {
    ushort8 o;
    if (t * 8 < (size_t)NN * DDIM) {
      const float4* xp = (const float4*)x;
      float4 a = xp[t * 2], b = xp[t * 2 + 1];
      o[0] = f2bf(a.x); o[1] = f2bf(a.y); o[2] = f2bf(a.z); o[3] = f2bf(a.w);
      o[4] = f2bf(b.x); o[5] = f2bf(b.y); o[6] = f2bf(b.z); o[7] = f2bf(b.w);
    } else {
      #pragma unroll
      for (int j = 0; j < 8; ++j) o[j] = 0;
    }
    *(ushort8*)(xb + t * 8) = o;
  }
  // W [k][n] f32 -> Wt [n][k] bf16, both layers
  for (int t = g0; t < DDIM * DDIM; t += stride) {
    int k = t >> 9, n = t & 511;
    Wt1[n * 512 + k] = f2bf(W1[t]);
    Wt2[n * 512 + k] = f2bf(W2[t]);
  }
  // zero degree counters
  for (int i = g0; i < NN; i += stride) cnt[i] = 0;
}

// ---------------- graph build ----------------
__global__ void k_deg(const int* __restrict__ ei, int* __restrict__ cnt,
                      int* __restrict__ pos) {
  int e = blockIdx.x * 256 + threadIdx.x;
  if (e < NE) {
    int d = ei[NE + e];                 // dst row
    pos[e] = atomicAdd(&cnt[d], 1);
  }
}

// single-block exclusive scan of cnt[NN] -> rowstart (replaces 3-kernel scan)
__global__ __launch_bounds__(1024) void k_scanb(const int* __restrict__ cnt,
                                                int* __restrict__ rowstart) {
  __shared__ int sd[1024];
  const int CH = (NN + 1023) / 1024;   // 49
  int t  = threadIdx.x;
  int b0 = t * CH;
  int s = 0;
  for (int j = 0; j < CH; ++j) {
    int i = b0 + j;
    if (i < NN) s += cnt[i];
  }
  int x = s;
  sd[t] = x; __syncthreads();
  for (int off = 1; off < 1024; off <<= 1) {
    int u = (t >= off) ? sd[t - off] : 0;
    __syncthreads();
    x += u; sd[t] = x;
    __syncthreads();
  }
  int run = x - s;                     // exclusive prefix of this chunk
  for (int j = 0; j < CH; ++j) {
    int i = b0 + j;
    if (i < NN) { rowstart[i] = run; run += cnt[i]; }
  }
  if (t == 0) rowstart[NN] = NE;
}

__global__ void k_fill(const int* __restrict__ ei, const float* __restrict__ ea,
                       const int* __restrict__ rowstart, const int* __restrict__ pos,
                       int* __restrict__ csr_src, float* __restrict__ csr_w) {
  int e = blockIdx.x * 256 + threadIdx.x;
  if (e < NE) {
    int d = ei[NE + e];
    int p = rowstart[d] + pos[e];
    csr_src[p] = ei[e];
    csr_w[p]   = ea[e];
  }
}

// dis1 = rsqrt(1 + sum_w in-edges)  (weighted, layer1)
// dis2 = rsqrt(1 + indegree)        (ones,    layer2)
__global__ void k_dis(const int* __restrict__ rowstart, const float* __restrict__ csr_w,
                      float* __restrict__ dis1, float* __restrict__ dis2) {
  int i = blockIdx.x * 256 + threadIdx.x;
  if (i < NN) {
    int p0 = rowstart[i], p1 = rowstart[i + 1];
    float s = 1.0f;
    for (int p = p0; p < p1; ++p) s += csr_w[p];
    dis1[i] = rsqrtf(s);
    dis2[i] = rsqrtf(1.0f + (float)(p1 - p0));
  }
}

// ---------------- GEMM: C[m][n] = sum_k A[m][k] * B[n][k], bf16 in/out, f32 acc ----
// PROVEN 58.7us config (R2 bench): single-buffered 2x16KB LDS, __syncthreads
// pair per K-step, global_load_lds width=16, rule-21 XOR swizzle (linear LDS
// dest + inverse-swizzled global src + swizzled ds_read), bijective XCD
// chunking with bcol fastest. Deep-pipeline variants (dbuf, counted vmcnt,
// 256^2 tile, B-direct, 4-slot ring) all measured equal or worse (R3-R8).
__global__ __launch_bounds__(256) void k_gemm(
    const unsigned short* __restrict__ A,   // [>=brow+128][512] bf16 row-major (M x K)
    const unsigned short* __restrict__ B,   // [512][512] bf16, n-major (N x K)
    unsigned short* __restrict__ C,         // [Mvalid][512] bf16
    int Mvalid)
{
  __shared__ unsigned short As[128 * 64];   // 16 KB
  __shared__ unsigned short Bs[128 * 64];   // 16 KB

  // bijective XCD swizzle (m204): nwg = gridDim.x, 8 XCDs
  int nwg  = gridDim.x;
  int orig = blockIdx.x;
  int q = nwg >> 3, r = nwg & 7;
  int xcd = orig & 7, xpos = orig >> 3;
  int wgid = (xcd < r ? xcd * (q + 1) : r * (q + 1) + (xcd - r) * q) + xpos;
  int bcol = (wgid & 3) * 128;              // N/128 = 4, fastest
  int brow = (wgid >> 2) * 128;

  int tid  = threadIdx.x;
  int lane = tid & 63;
  int wave = tid >> 6;
  int wr = wave >> 1, wc = wave & 1;        // 2x2 waves -> 64x64 each
  int r16 = lane & 15;
  int kl16 = (lane >> 4) * 16;              // byte offset of this lane-group's k8

  const f32x4 zero = {0.f, 0.f, 0.f, 0.f};
  f32x4 acc[4][4];
  #pragma unroll
  for (int m = 0; m < 4; ++m)
    #pragma unroll
    for (int n = 0; n < 4; ++n) acc[m][n] = zero;

  for (int kt = 0; kt < 512; kt += 64) {
    // stage 32 KB: 2048 chunks of 16B, 8 per thread (4 A + 4 B).
    // physical LDS linear in chunk index; global source inverse-swizzled.
    #pragma unroll
    for (int i = 0; i < 4; ++i) {
      int c   = tid + (i << 8);             // 0..1023
      int row = c >> 3;                     // 0..127
      int qo  = ((c & 7) << 4) ^ ((row & 7) << 4);   // logical byte col in [0,128)
      gload_lds16(A + (size_t)(brow + row) * 512 + kt + (qo >> 1),
                  (char*)As + (size_t)c * 16);
      gload_lds16(B + (size_t)(bcol + row) * 512 + kt + (qo >> 1),
                  (char*)Bs + (size_t)c * 16);
    }
    __syncthreads();

    #pragma unroll
    for (int ks = 0; ks < 2; ++ks) {
      short8 af[4], bfr[4];
      int qo = kl16 + ks * 64;              // logical byte col of fragment
      #pragma unroll
      for (int m = 0; m < 4; ++m) {
        int row = wr * 64 + m * 16 + r16;
        af[m] = *(const short8*)((const char*)As + row * 128 + (qo ^ ((row & 7) << 4)));
      }
      #pragma unroll
      for (int n = 0; n < 4; ++n) {
        int row = wc * 64 + n * 16 + r16;
        bfr[n] = *(const short8*)((const char*)Bs + row * 128 + (qo ^ ((row & 7) << 4)));
      }
      #pragma unroll
      for (int m = 0; m < 4; ++m)
        #pragma unroll
        for (int n = 0; n < 4; ++n)
          acc[m][n] = __builtin_amdgcn_mfma_f32_16x16x32_bf16(af[m], bfr[n], acc[m][n], 0, 0, 0);
    }
    __syncthreads();
  }

  int rbase = (lane >> 4) * 4;   // C/D: col=lane&15, row=(lane>>4)*4+reg
  int ccol  = lane & 15;
  #pragma unroll
  for (int m = 0; m < 4; ++m)
    #pragma unroll
    for (int n = 0; n < 4; ++n)
      #pragma unroll
      for (int i = 0; i < 4; ++i) {
        int grow = brow + wr * 64 + m * 16 + rbase + i;
        if (grow < Mvalid) {
          int gcol = bcol + wc * 64 + n * 16 + ccol;
          C[(size_t)grow * 512 + gcol] = f2bf(acc[m][n][i]);
        }
      }
}

// ---------------- aggregation: out[i] = b + dis_i^2*h[i] + sum_e dis_s*w*dis_i*h[s] ----
// one wave per node; lane owns dims [lane*8, lane*8+8); 2-way edge unroll to
// overlap the dependent idx->gather chains of consecutive edges.
__global__ __launch_bounds__(256) void k_agg(
    const unsigned short* __restrict__ h, const float* __restrict__ dis,
    const float* __restrict__ bias, const int* __restrict__ rowstart,
    const int* __restrict__ csr_src, const float* __restrict__ csr_w,
    int useW, void* __restrict__ outp, int outBf16, int nrows)
{
  int node = blockIdx.x * 4 + (threadIdx.x >> 6);
  int lane = threadIdx.x & 63;
  if (node >= nrows) return;
  if (node >= NN) {                        // pad row (layer-1 bf16 output only)
    ((uint4*)outp)[(size_t)node * 64 + lane] = make_uint4(0, 0, 0, 0);
    return;
  }
  const uint4* hp = (const uint4*)h;
  float di = dis[node];
  float t0[8], t1[8], acc[8];
  uint4 hv = hp[(size_t)node * 64 + lane];
  unpack8(hv, t0);
  float selfc = di * di;                   // self-loop: dis_i * 1 * dis_i
  #pragma unroll
  for (int j = 0; j < 8; ++j) acc[j] = t0[j] * selfc;
  int p0 = rowstart[node], p1 = rowstart[node + 1];
  int p = p0;
  for (; p + 2 <= p1; p += 2) {
    int s0 = csr_src[p], s1 = csr_src[p + 1];
    float c0 = dis[s0] * di, c1 = dis[s1] * di;
    if (useW) { c0 *= csr_w[p]; c1 *= csr_w[p + 1]; }
    uint4 v0 = hp[(size_t)s0 * 64 + lane];
    uint4 v1 = hp[(size_t)s1 * 64 + lane];
    unpack8(v0, t0); unpack8(v1, t1);
    #pragma unroll
    for (int j = 0; j < 8; ++j) acc[j] += c0 * t0[j];
    #pragma unroll
    for (int j = 0; j < 8; ++j) acc[j] += c1 * t1[j];
  }
  if (p < p1) {
    int s = csr_src[p];
    float c = dis[s] * di;
    if (useW) c *= csr_w[p];
    uint4 v = hp[(size_t)s * 64 + lane];
    unpack8(v, t0);
    #pragma unroll
    for (int j = 0; j < 8; ++j) acc[j] += c * t0[j];
  }
  const float4* bp = (const float4*)bias;
  float4 b0 = bp[lane * 2], b1 = bp[lane * 2 + 1];
  acc[0] += b0.x; acc[1] += b0.y; acc[2] += b0.z; acc[3] += b0.w;
  acc[4] += b1.x; acc[5] += b1.y; acc[6] += b1.z; acc[7] += b1.w;
  if (outBf16) {                           // layer 1: fuse ReLU + bf16 cast
    ushort8 o;
    #pragma unroll
    for (int j = 0; j < 8; ++j) o[j] = f2bf(fmaxf(acc[j], 0.0f));
    *(ushort8*)((unsigned short*)outp + (size_t)node * 512 + lane * 8) = o;
  } else {                                 // layer 2: f32 final output
    float* op = (float*)outp + (size_t)node * 512 + lane * 8;
    *(float4*)op       = make_float4(acc[0], acc[1], acc[2], acc[3]);
    *(float4*)(op + 4) = make_float4(acc[4], acc[5], acc[6], acc[7]);
  }
}

// ---------------- workspace layout ----------------
constexpr size_t al(size_t x) { return (x + 255) & ~(size_t)255; }
constexpr size_t SZ_XB  = (size_t)MPAD * DDIM * 2;   // bf16 x (padded); reused as relu(h1)
constexpr size_t SZ_H   = (size_t)NN   * DDIM * 2;   // bf16 h1; reused as h2
constexpr size_t SZ_WT  = (size_t)DDIM * DDIM * 2;
constexpr size_t O_XB   = 0;
constexpr size_t O_H    = al(O_XB + SZ_XB);
constexpr size_t O_WT1  = al(O_H + SZ_H);
constexpr size_t O_WT2  = al(O_WT1 + SZ_WT);
constexpr size_t O_DIS1 = al(O_WT2 + SZ_WT);
constexpr size_t O_DIS2 = al(O_DIS1 + (size_t)NN * 4);
constexpr size_t O_CNT  = al(O_DIS2 + (size_t)NN * 4);
constexpr size_t O_RS   = al(O_CNT + (size_t)NN * 4);
constexpr size_t O_POS  = al(O_RS + (size_t)(NN + 1) * 4);
constexpr size_t O_CSRS = al(O_POS + (size_t)NE * 4);
constexpr size_t O_CSRW = al(O_CSRS + (size_t)NE * 4);
constexpr size_t WS_NEED = al(O_CSRW + (size_t)NE * 4);

extern "C" void kernel_launch(void* const* d_in, const int* in_sizes, int n_in,
                              void* d_out, int out_size, void* d_ws, size_t ws_size,
                              hipStream_t stream) {
  const float* x  = (const float*)d_in[0];
  const int*   ei = (const int*)d_in[1];
  const float* ea = (const float*)d_in[2];
  const float* W1 = (const float*)d_in[3];
  const float* b1 = (const float*)d_in[4];
  const float* W2 = (const float*)d_in[5];
  const float* b2 = (const float*)d_in[6];
  if (ws_size < WS_NEED) return;

  char* ws = (char*)d_ws;
  unsigned short* xb   = (unsigned short*)(ws + O_XB);   // also relu(h1) later
  unsigned short* h    = (unsigned short*)(ws + O_H);    // h1, then h2
  unsigned short* Wt1  = (unsigned short*)(ws + O_WT1);
  unsigned short* Wt2  = (unsigned short*)(ws + O_WT2);
  float* dis1 = (float*)(ws + O_DIS1);
  float* dis2 = (float*)(ws + O_DIS2);
  int*   cnt  = (int*)(ws + O_CNT);
  int*   rs   = (int*)(ws + O_RS);
  int*   pos  = (int*)(ws + O_POS);
  int*   csrs = (int*)(ws + O_CSRS);
  float* csrw = (float*)(ws + O_CSRW);

  // fused conversions + counter init (1 launch instead of 3)
  k_prep <<<2048, 256, 0, stream>>>(x, W1, W2, xb, Wt1, Wt2, cnt);
  // graph build (4 launches instead of 6)
  k_deg  <<<(NE + 255) / 256, 256, 0, stream>>>(ei, cnt, pos);
  k_scanb<<<1, 1024, 0, stream>>>(cnt, rs);
  k_fill <<<(NE + 255) / 256, 256, 0, stream>>>(ei, ea, rs, pos, csrs, csrw);
  k_dis  <<<NB_SCAN, 256, 0, stream>>>(rs, csrw, dis1, dis2);

  int ngemm = (MPAD / 128) * (DDIM / 128);   // 1564
  // layer 1
  k_gemm<<<ngemm, 256, 0, stream>>>(xb, Wt1, h, NN);
  k_agg <<<MPAD / 4, 256, 0, stream>>>(h, dis1, b1, rs, csrs, csrw,
                                       1, (void*)xb, 1, MPAD);   // relu->bf16 into xb
  // layer 2
  k_gemm<<<ngemm, 256, 0, stream>>>(xb, Wt2, h, NN);
  k_agg <<<(NN + 3) / 4, 256, 0, stream>>>(h, dis2, b2, rs, csrs, csrw,
                                           0, d_out, 0, NN);     // f32 final
}

// Round 10
// 232.433 us; speedup vs baseline: 1.3565x; 1.3565x over previous
//
#include <hip/hip_runtime.h>
#include <hip/hip_bf16.h>

#define NN   50000
#define NE   160000
#define DDIM 512
#define MPAD 50048          // 391 * 128
#define NB_SCAN 196         // ceil(NN/256)

typedef __attribute__((ext_vector_type(8))) short  short8;
typedef __attribute__((ext_vector_type(8))) unsigned short ushort8;
typedef __attribute__((ext_vector_type(4))) float  f32x4;

__device__ __forceinline__ unsigned short f2bf(float f) {
  union { float f; unsigned u; } v; v.f = f;
  unsigned u = v.u;
  unsigned r = (u + 0x7FFFu + ((u >> 16) & 1u)) >> 16;   // RNE
  return (unsigned short)r;
}
__device__ __forceinline__ float bf2f(unsigned short s) {
  union { unsigned u; float f; } v; v.u = ((unsigned)s) << 16;
  return v.f;
}
__device__ __forceinline__ void unpack8(uint4 v, float* t) {
  t[0] = bf2f(v.x & 0xffff); t[1] = bf2f(v.x >> 16);
  t[2] = bf2f(v.y & 0xffff); t[3] = bf2f(v.y >> 16);
  t[4] = bf2f(v.z & 0xffff); t[5] = bf2f(v.z >> 16);
  t[6] = bf2f(v.w & 0xffff); t[7] = bf2f(v.w >> 16);
}
__device__ __forceinline__ void gload_lds16(const void* g, void* l) {
  __builtin_amdgcn_global_load_lds(
      (const __attribute__((address_space(1))) unsigned int*)g,
      (__attribute__((address_space(3))) unsigned int*)l, 16, 0, 0);
}

// ---------------- fused prep: cvt_x + cvt_w (both) + cnt zero ----------------
__global__ __launch_bounds__(256) void k_prep(
    const float* __restrict__ x, const float* __restrict__ W1,
    const float* __restrict__ W2, unsigned short* __restrict__ xb,
    unsigned short* __restrict__ Wt1, unsigned short* __restrict__ Wt2,
    int* __restrict__ cnt)
{
  int stride = gridDim.x * 256;
  int g0 = blockIdx.x * 256 + threadIdx.x;
  // x f32 -> bf16 (padded rows zeroed), 8 elems per iteration
  for (size_t t = g0; t < (size_t)MPAD * 64; t += stride) {
    ushort8 o;
    if (t * 8 < (size_t)NN * DDIM) {
      const float4* xp = (const float4*)x;
      float4 a = xp[t * 2], b = xp[t * 2 + 1];
      o[0] = f2bf(a.x); o[1] = f2bf(a.y); o[2] = f2bf(a.z); o[3] = f2bf(a.w);
      o[4] = f2bf(b.x); o[5] = f2bf(b.y); o[6] = f2bf(b.z); o[7] = f2bf(b.w);
    } else {
      #pragma unroll
      for (int j = 0; j < 8; ++j) o[j] = 0;
    }
    *(ushort8*)(xb + t * 8) = o;
  }
  // W [k][n] f32 -> Wt [n][k] bf16, both layers
  for (int t = g0; t < DDIM * DDIM; t += stride) {
    int k = t >> 9, n = t & 511;
    Wt1[n * 512 + k] = f2bf(W1[t]);
    Wt2[n * 512 + k] = f2bf(W2[t]);
  }
  // zero degree counters
  for (int i = g0; i < NN; i += stride) cnt[i] = 0;
}

// ---------------- graph build ----------------
__global__ void k_deg(const int* __restrict__ ei, int* __restrict__ cnt,
                      int* __restrict__ pos) {
  int e = blockIdx.x * 256 + threadIdx.x;
  if (e < NE) {
    int d = ei[NE + e];                 // dst row
    pos[e] = atomicAdd(&cnt[d], 1);
  }
}

// proven 3-kernel scan (R2-R7): per-block reduce -> single-block scan of block
// sums -> per-block exclusive scan. (R8's single-block k_scanb was 94us:
// 1 CU + uncoalesced chunk-per-thread reads. Reverted.)
__global__ void k_scan1(const int* __restrict__ cnt, int* __restrict__ bsum) {
  __shared__ int sd[256];
  int t = threadIdx.x;
  int i = blockIdx.x * 256 + t;
  sd[t] = (i < NN) ? cnt[i] : 0;
  __syncthreads();
  for (int off = 128; off > 0; off >>= 1) {
    if (t < off) sd[t] += sd[t + off];
    __syncthreads();
  }
  if (t == 0) bsum[blockIdx.x] = sd[0];
}

__global__ void k_scan2(const int* __restrict__ bsum, int* __restrict__ boff,
                        int* __restrict__ rowstart) {
  __shared__ int sd[256];
  int t = threadIdx.x;
  int v = (t < NB_SCAN) ? bsum[t] : 0;
  int x = v;
  sd[t] = x;
  __syncthreads();
  for (int off = 1; off < 256; off <<= 1) {
    int u = (t >= off) ? sd[t - off] : 0;
    __syncthreads();
    x += u; sd[t] = x;
    __syncthreads();
  }
  if (t < NB_SCAN) boff[t] = x - v;     // exclusive
  if (t == 0) rowstart[NN] = NE;
}

__global__ void k_scan3(const int* __restrict__ cnt, const int* __restrict__ boff,
                        int* __restrict__ rowstart) {
  __shared__ int sd[256];
  int t = threadIdx.x;
  int i = blockIdx.x * 256 + t;
  int v = (i < NN) ? cnt[i] : 0;
  int x = v;
  sd[t] = x;
  __syncthreads();
  for (int off = 1; off < 256; off <<= 1) {
    int u = (t >= off) ? sd[t - off] : 0;
    __syncthreads();
    x += u; sd[t] = x;
    __syncthreads();
  }
  if (i < NN) rowstart[i] = boff[blockIdx.x] + x - v;   // exclusive
}

__global__ void k_fill(const int* __restrict__ ei, const float* __restrict__ ea,
                       const int* __restrict__ rowstart, const int* __restrict__ pos,
                       int* __restrict__ csr_src, float* __restrict__ csr_w) {
  int e = blockIdx.x * 256 + threadIdx.x;
  if (e < NE) {
    int d = ei[NE + e];
    int p = rowstart[d] + pos[e];
    csr_src[p] = ei[e];
    csr_w[p]   = ea[e];
  }
}

// dis1 = rsqrt(1 + sum_w in-edges)  (weighted, layer1)
// dis2 = rsqrt(1 + indegree)        (ones,    layer2)
__global__ void k_dis(const int* __restrict__ rowstart, const float* __restrict__ csr_w,
                      float* __restrict__ dis1, float* __restrict__ dis2) {
  int i = blockIdx.x * 256 + threadIdx.x;
  if (i < NN) {
    int p0 = rowstart[i], p1 = rowstart[i + 1];
    float s = 1.0f;
    for (int p = p0; p < p1; ++p) s += csr_w[p];
    dis1[i] = rsqrtf(s);
    dis2[i] = rsqrtf(1.0f + (float)(p1 - p0));
  }
}

// ---------------- GEMM: C[m][n] = sum_k A[m][k] * B[n][k], bf16 in/out, f32 acc ----
// PROVEN 58.7us config (R2 bench): single-buffered 2x16KB LDS, __syncthreads
// pair per K-step, global_load_lds width=16, rule-21 XOR swizzle (linear LDS
// dest + inverse-swizzled global src + swizzled ds_read), bijective XCD
// chunking with bcol fastest. Deep-pipeline variants (dbuf, counted vmcnt,
// 256^2 tile, B-direct, 4-slot ring) all measured equal or worse (R3-R8).
__global__ __launch_bounds__(256) void k_gemm(
    const unsigned short* __restrict__ A,   // [>=brow+128][512] bf16 row-major (M x K)
    const unsigned short* __restrict__ B,   // [512][512] bf16, n-major (N x K)
    unsigned short* __restrict__ C,         // [Mvalid][512] bf16
    int Mvalid)
{
  __shared__ unsigned short As[128 * 64];   // 16 KB
  __shared__ unsigned short Bs[128 * 64];   // 16 KB

  // bijective XCD swizzle (m204): nwg = gridDim.x, 8 XCDs
  int nwg  = gridDim.x;
  int orig = blockIdx.x;
  int q = nwg >> 3, r = nwg & 7;
  int xcd = orig & 7, xpos = orig >> 3;
  int wgid = (xcd < r ? xcd * (q + 1) : r * (q + 1) + (xcd - r) * q) + xpos;
  int bcol = (wgid & 3) * 128;              // N/128 = 4, fastest
  int brow = (wgid >> 2) * 128;

  int tid  = threadIdx.x;
  int lane = tid & 63;
  int wave = tid >> 6;
  int wr = wave >> 1, wc = wave & 1;        // 2x2 waves -> 64x64 each
  int r16 = lane & 15;
  int kl16 = (lane >> 4) * 16;              // byte offset of this lane-group's k8

  const f32x4 zero = {0.f, 0.f, 0.f, 0.f};
  f32x4 acc[4][4];
  #pragma unroll
  for (int m = 0; m < 4; ++m)
    #pragma unroll
    for (int n = 0; n < 4; ++n) acc[m][n] = zero;

  for (int kt = 0; kt < 512; kt += 64) {
    // stage 32 KB: 2048 chunks of 16B, 8 per thread (4 A + 4 B).
    // physical LDS linear in chunk index; global source inverse-swizzled.
    #pragma unroll
    for (int i = 0; i < 4; ++i) {
      int c   = tid + (i << 8);             // 0..1023
      int row = c >> 3;                     // 0..127
      int qo  = ((c & 7) << 4) ^ ((row & 7) << 4);   // logical byte col in [0,128)
      gload_lds16(A + (size_t)(brow + row) * 512 + kt + (qo >> 1),
                  (char*)As + (size_t)c * 16);
      gload_lds16(B + (size_t)(bcol + row) * 512 + kt + (qo >> 1),
                  (char*)Bs + (size_t)c * 16);
    }
    __syncthreads();

    #pragma unroll
    for (int ks = 0; ks < 2; ++ks) {
      short8 af[4], bfr[4];
      int qo = kl16 + ks * 64;              // logical byte col of fragment
      #pragma unroll
      for (int m = 0; m < 4; ++m) {
        int row = wr * 64 + m * 16 + r16;
        af[m] = *(const short8*)((const char*)As + row * 128 + (qo ^ ((row & 7) << 4)));
      }
      #pragma unroll
      for (int n = 0; n < 4; ++n) {
        int row = wc * 64 + n * 16 + r16;
        bfr[n] = *(const short8*)((const char*)Bs + row * 128 + (qo ^ ((row & 7) << 4)));
      }
      #pragma unroll
      for (int m = 0; m < 4; ++m)
        #pragma unroll
        for (int n = 0; n < 4; ++n)
          acc[m][n] = __builtin_amdgcn_mfma_f32_16x16x32_bf16(af[m], bfr[n], acc[m][n], 0, 0, 0);
    }
    __syncthreads();
  }

  int rbase = (lane >> 4) * 4;   // C/D: col=lane&15, row=(lane>>4)*4+reg
  int ccol  = lane & 15;
  #pragma unroll
  for (int m = 0; m < 4; ++m)
    #pragma unroll
    for (int n = 0; n < 4; ++n)
      #pragma unroll
      for (int i = 0; i < 4; ++i) {
        int grow = brow + wr * 64 + m * 16 + rbase + i;
        if (grow < Mvalid) {
          int gcol = bcol + wc * 64 + n * 16 + ccol;
          C[(size_t)grow * 512 + gcol] = f2bf(acc[m][n][i]);
        }
      }
}

// ---------------- aggregation: out[i] = b + dis_i^2*h[i] + sum_e dis_s*w*dis_i*h[s] ----
// one wave per node; lane owns dims [lane*8, lane*8+8); 2-way edge unroll to
// overlap the dependent idx->gather chains of consecutive edges.
__global__ __launch_bounds__(256) void k_agg(
    const unsigned short* __restrict__ h, const float* __restrict__ dis,
    const float* __restrict__ bias, const int* __restrict__ rowstart,
    const int* __restrict__ csr_src, const float* __restrict__ csr_w,
    int useW, void* __restrict__ outp, int outBf16, int nrows)
{
  int node = blockIdx.x * 4 + (threadIdx.x >> 6);
  int lane = threadIdx.x & 63;
  if (node >= nrows) return;
  if (node >= NN) {                        // pad row (layer-1 bf16 output only)
    ((uint4*)outp)[(size_t)node * 64 + lane] = make_uint4(0, 0, 0, 0);
    return;
  }
  const uint4* hp = (const uint4*)h;
  float di = dis[node];
  float t0[8], t1[8], acc[8];
  uint4 hv = hp[(size_t)node * 64 + lane];
  unpack8(hv, t0);
  float selfc = di * di;                   // self-loop: dis_i * 1 * dis_i
  #pragma unroll
  for (int j = 0; j < 8; ++j) acc[j] = t0[j] * selfc;
  int p0 = rowstart[node], p1 = rowstart[node + 1];
  int p = p0;
  for (; p + 2 <= p1; p += 2) {
    int s0 = csr_src[p], s1 = csr_src[p + 1];
    float c0 = dis[s0] * di, c1 = dis[s1] * di;
    if (useW) { c0 *= csr_w[p]; c1 *= csr_w[p + 1]; }
    uint4 v0 = hp[(size_t)s0 * 64 + lane];
    uint4 v1 = hp[(size_t)s1 * 64 + lane];
    unpack8(v0, t0); unpack8(v1, t1);
    #pragma unroll
    for (int j = 0; j < 8; ++j) acc[j] += c0 * t0[j];
    #pragma unroll
    for (int j = 0; j < 8; ++j) acc[j] += c1 * t1[j];
  }
  if (p < p1) {
    int s = csr_src[p];
    float c = dis[s] * di;
    if (useW) c *= csr_w[p];
    uint4 v = hp[(size_t)s * 64 + lane];
    unpack8(v, t0);
    #pragma unroll
    for (int j = 0; j < 8; ++j) acc[j] += c * t0[j];
  }
  const float4* bp = (const float4*)bias;
  float4 b0 = bp[lane * 2], b1 = bp[lane * 2 + 1];
  acc[0] += b0.x; acc[1] += b0.y; acc[2] += b0.z; acc[3] += b0.w;
  acc[4] += b1.x; acc[5] += b1.y; acc[6] += b1.z; acc[7] += b1.w;
  if (outBf16) {                           // layer 1: fuse ReLU + bf16 cast
    ushort8 o;
    #pragma unroll
    for (int j = 0; j < 8; ++j) o[j] = f2bf(fmaxf(acc[j], 0.0f));
    *(ushort8*)((unsigned short*)outp + (size_t)node * 512 + lane * 8) = o;
  } else {                                 // layer 2: f32 final output
    float* op = (float*)outp + (size_t)node * 512 + lane * 8;
    *(float4*)op       = make_float4(acc[0], acc[1], acc[2], acc[3]);
    *(float4*)(op + 4) = make_float4(acc[4], acc[5], acc[6], acc[7]);
  }
}

// ---------------- workspace layout ----------------
constexpr size_t al(size_t x) { return (x + 255) & ~(size_t)255; }
constexpr size_t SZ_XB  = (size_t)MPAD * DDIM * 2;   // bf16 x (padded); reused as relu(h1)
constexpr size_t SZ_H   = (size_t)NN   * DDIM * 2;   // bf16 h1; reused as h2
constexpr size_t SZ_WT  = (size_t)DDIM * DDIM * 2;
constexpr size_t O_XB   = 0;
constexpr size_t O_H    = al(O_XB + SZ_XB);
constexpr size_t O_WT1  = al(O_H + SZ_H);
constexpr size_t O_WT2  = al(O_WT1 + SZ_WT);
constexpr size_t O_DIS1 = al(O_WT2 + SZ_WT);
constexpr size_t O_DIS2 = al(O_DIS1 + (size_t)NN * 4);
constexpr size_t O_CNT  = al(O_DIS2 + (size_t)NN * 4);
constexpr size_t O_RS   = al(O_CNT + (size_t)NN * 4);
constexpr size_t O_POS  = al(O_RS + (size_t)(NN + 1) * 4);
constexpr size_t O_CSRS = al(O_POS + (size_t)NE * 4);
constexpr size_t O_CSRW = al(O_CSRS + (size_t)NE * 4);
constexpr size_t O_BSUM = al(O_CSRW + (size_t)NE * 4);
constexpr size_t O_BOFF = al(O_BSUM + (size_t)NB_SCAN * 4);
constexpr size_t WS_NEED = al(O_BOFF + (size_t)NB_SCAN * 4);

extern "C" void kernel_launch(void* const* d_in, const int* in_sizes, int n_in,
                              void* d_out, int out_size, void* d_ws, size_t ws_size,
                              hipStream_t stream) {
  const float* x  = (const float*)d_in[0];
  const int*   ei = (const int*)d_in[1];
  const float* ea = (const float*)d_in[2];
  const float* W1 = (const float*)d_in[3];
  const float* b1 = (const float*)d_in[4];
  const float* W2 = (const float*)d_in[5];
  const float* b2 = (const float*)d_in[6];
  if (ws_size < WS_NEED) return;

  char* ws = (char*)d_ws;
  unsigned short* xb   = (unsigned short*)(ws + O_XB);   // also relu(h1) later
  unsigned short* h    = (unsigned short*)(ws + O_H);    // h1, then h2
  unsigned short* Wt1  = (unsigned short*)(ws + O_WT1);
  unsigned short* Wt2  = (unsigned short*)(ws + O_WT2);
  float* dis1 = (float*)(ws + O_DIS1);
  float* dis2 = (float*)(ws + O_DIS2);
  int*   cnt  = (int*)(ws + O_CNT);
  int*   rs   = (int*)(ws + O_RS);
  int*   pos  = (int*)(ws + O_POS);
  int*   csrs = (int*)(ws + O_CSRS);
  float* csrw = (float*)(ws + O_CSRW);
  int*   bsum = (int*)(ws + O_BSUM);
  int*   boff = (int*)(ws + O_BOFF);

  // fused conversions + counter init (1 launch instead of 3)
  k_prep <<<2048, 256, 0, stream>>>(x, W1, W2, xb, Wt1, Wt2, cnt);
  // graph build (proven 3-kernel scan)
  k_deg  <<<(NE + 255) / 256, 256, 0, stream>>>(ei, cnt, pos);
  k_scan1<<<NB_SCAN, 256, 0, stream>>>(cnt, bsum);
  k_scan2<<<1, 256, 0, stream>>>(bsum, boff, rs);
  k_scan3<<<NB_SCAN, 256, 0, stream>>>(cnt, boff, rs);
  k_fill <<<(NE + 255) / 256, 256, 0, stream>>>(ei, ea, rs, pos, csrs, csrw);
  k_dis  <<<NB_SCAN, 256, 0, stream>>>(rs, csrw, dis1, dis2);

  int ngemm = (MPAD / 128) * (DDIM / 128);   // 1564
  // layer 1
  k_gemm<<<ngemm, 256, 0, stream>>>(xb, Wt1, h, NN);
  k_agg <<<MPAD / 4, 256, 0, stream>>>(h, dis1, b1, rs, csrs, csrw,
                                       1, (void*)xb, 1, MPAD);   // relu->bf16 into xb
  // layer 2
  k_gemm<<<ngemm, 256, 0, stream>>>(xb, Wt2, h, NN);
  k_agg <<<(NN + 3) / 4, 256, 0, stream>>>(h, dis2, b2, rs, csrs, csrw,
                                           0, d_out, 0, NN);     // f32 final
}

// Round 12
// 220.940 us; speedup vs baseline: 1.4270x; 1.0520x over previous
//
#include <hip/hip_runtime.h>
#include <hip/hip_bf16.h>

#define NN   50000
#define NE   160000
#define DDIM 512
#define MPAD 50048          // 391 * 128
#define NB_SCAN 196         // ceil(NN/256)

typedef __attribute__((ext_vector_type(8))) short  short8;
typedef __attribute__((ext_vector_type(8))) unsigned short ushort8;
typedef __attribute__((ext_vector_type(4))) float  f32x4;

__device__ __forceinline__ unsigned short f2bf(float f) {
  union { float f; unsigned u; } v; v.f = f;
  unsigned u = v.u;
  unsigned r = (u + 0x7FFFu + ((u >> 16) & 1u)) >> 16;   // RNE
  return (unsigned short)r;
}
__device__ __forceinline__ float bf2f(unsigned short s) {
  union { unsigned u; float f; } v; v.u = ((unsigned)s) << 16;
  return v.f;
}
__device__ __forceinline__ void unpack8(uint4 v, float* t) {
  t[0] = bf2f(v.x & 0xffff); t[1] = bf2f(v.x >> 16);
  t[2] = bf2f(v.y & 0xffff); t[3] = bf2f(v.y >> 16);
  t[4] = bf2f(v.z & 0xffff); t[5] = bf2f(v.z >> 16);
  t[6] = bf2f(v.w & 0xffff); t[7] = bf2f(v.w >> 16);
}
__device__ __forceinline__ void gload_lds16(const void* g, void* l) {
  __builtin_amdgcn_global_load_lds(
      (const __attribute__((address_space(1))) unsigned int*)g,
      (__attribute__((address_space(3))) unsigned int*)l, 16, 0, 0);
}

// ---------------- fused prep: cvt_x + cvt_w (both) + cnt zero ----------------
__global__ __launch_bounds__(256) void k_prep(
    const float* __restrict__ x, const float* __restrict__ W1,
    const float* __restrict__ W2, unsigned short* __restrict__ xb,
    unsigned short* __restrict__ Wt1, unsigned short* __restrict__ Wt2,
    int* __restrict__ cnt)
{
  int stride = gridDim.x * 256;
  int g0 = blockIdx.x * 256 + threadIdx.x;
  // x f32 -> bf16 (padded rows zeroed), 8 elems per iteration
  for (size_t t = g0; t < (size_t)MPAD * 64; t += stride) {
    ushort8 o;
    if (t * 8 < (size_t)NN * DDIM) {
      const float4* xp = (const float4*)x;
      float4 a = xp[t * 2], b = xp[t * 2 + 1];
      o[0] = f2bf(a.x); o[1] = f2bf(a.y); o[2] = f2bf(a.z); o[3] = f2bf(a.w);
      o[4] = f2bf(b.x); o[5] = f2bf(b.y); o[6] = f2bf(b.z); o[7] = f2bf(b.w);
    } else {
      #pragma unroll
      for (int j = 0; j < 8; ++j) o[j] = 0;
    }
    *(ushort8*)(xb + t * 8) = o;
  }
  // W [k][n] f32 -> Wt [n][k] bf16, both layers
  for (int t = g0; t < DDIM * DDIM; t += stride) {
    int k = t >> 9, n = t & 511;
    Wt1[n * 512 + k] = f2bf(W1[t]);
    Wt2[n * 512 + k] = f2bf(W2[t]);
  }
  // zero degree counters
  for (int i = g0; i < NN; i += stride) cnt[i] = 0;
}

// ---------------- graph build ----------------
__global__ void k_deg(const int* __restrict__ ei, int* __restrict__ cnt,
                      int* __restrict__ pos) {
  int e = blockIdx.x * 256 + threadIdx.x;
  if (e < NE) {
    int d = ei[NE + e];                 // dst row
    pos[e] = atomicAdd(&cnt[d], 1);
  }
}

// proven 3-kernel scan (R2-R7). (R8's single-block scan was 94us; reverted.)
__global__ void k_scan1(const int* __restrict__ cnt, int* __restrict__ bsum) {
  __shared__ int sd[256];
  int t = threadIdx.x;
  int i = blockIdx.x * 256 + t;
  sd[t] = (i < NN) ? cnt[i] : 0;
  __syncthreads();
  for (int off = 128; off > 0; off >>= 1) {
    if (t < off) sd[t] += sd[t + off];
    __syncthreads();
  }
  if (t == 0) bsum[blockIdx.x] = sd[0];
}

__global__ void k_scan2(const int* __restrict__ bsum, int* __restrict__ boff,
                        int* __restrict__ rowstart) {
  __shared__ int sd[256];
  int t = threadIdx.x;
  int v = (t < NB_SCAN) ? bsum[t] : 0;
  int x = v;
  sd[t] = x;
  __syncthreads();
  for (int off = 1; off < 256; off <<= 1) {
    int u = (t >= off) ? sd[t - off] : 0;
    __syncthreads();
    x += u; sd[t] = x;
    __syncthreads();
  }
  if (t < NB_SCAN) boff[t] = x - v;     // exclusive
  if (t == 0) rowstart[NN] = NE;
}

__global__ void k_scan3(const int* __restrict__ cnt, const int* __restrict__ boff,
                        int* __restrict__ rowstart) {
  __shared__ int sd[256];
  int t = threadIdx.x;
  int i = blockIdx.x * 256 + t;
  int v = (i < NN) ? cnt[i] : 0;
  int x = v;
  sd[t] = x;
  __syncthreads();
  for (int off = 1; off < 256; off <<= 1) {
    int u = (t >= off) ? sd[t - off] : 0;
    __syncthreads();
    x += u; sd[t] = x;
    __syncthreads();
  }
  if (i < NN) rowstart[i] = boff[blockIdx.x] + x - v;   // exclusive
}

// CSR fill: packed {src, w-bits} per edge (one 8B load in consumers)
__global__ void k_fill(const int* __restrict__ ei, const float* __restrict__ ea,
                       const int* __restrict__ rowstart, const int* __restrict__ pos,
                       int2* __restrict__ csre) {
  int e = blockIdx.x * 256 + threadIdx.x;
  if (e < NE) {
    int d = ei[NE + e];
    int p = rowstart[d] + pos[e];
    csre[p] = make_int2(ei[e], __float_as_int(ea[e]));
  }
}

// dis1 = rsqrt(1 + sum_w in-edges)  (weighted, layer1)
// dis2 = rsqrt(1 + indegree)        (ones,    layer2)
__global__ void k_dis(const int* __restrict__ rowstart, const int2* __restrict__ csre,
                      float* __restrict__ dis1, float* __restrict__ dis2) {
  int i = blockIdx.x * 256 + threadIdx.x;
  if (i < NN) {
    int p0 = rowstart[i], p1 = rowstart[i + 1];
    float s = 1.0f;
    for (int p = p0; p < p1; ++p) s += __int_as_float(csre[p].y);
    dis1[i] = rsqrtf(s);
    dis2[i] = rsqrtf(1.0f + (float)(p1 - p0));
  }
}

// per-edge coefficient precompute: removes the dependent dis[s] load from the
// agg hot loop (3-deep load chain -> 2-deep).
// e1[p] = {src, ea*dis1[src]}   (layer-1: c = e1.w * dis1[dst])
// e2[p] = {src, dis2[src]}      (layer-2: c = e2.w * dis2[dst])
__global__ void k_epre(const int2* __restrict__ csre, const float* __restrict__ dis1,
                       const float* __restrict__ dis2, int2* __restrict__ e1,
                       int2* __restrict__ e2) {
  int e = blockIdx.x * 256 + threadIdx.x;
  if (e < NE) {
    int2 pr = csre[e];
    int s = pr.x;
    float w = __int_as_float(pr.y);
    e1[e] = make_int2(s, __float_as_int(w * dis1[s]));
    e2[e] = make_int2(s, __float_as_int(dis2[s]));
  }
}

// ---------------- GEMM: C[m][n] = sum_k A[m][k] * B[n][k], bf16 in/out, f32 acc ----
// PROVEN 58.7us config (R2 bench): single-buffered 2x16KB LDS, __syncthreads
// pair per K-step, global_load_lds width=16, rule-21 XOR swizzle, bijective XCD
// chunking with bcol fastest. Deep-pipeline variants all equal/worse (R3-R8).
__global__ __launch_bounds__(256) void k_gemm(
    const unsigned short* __restrict__ A,   // [>=brow+128][512] bf16 row-major (M x K)
    const unsigned short* __restrict__ B,   // [512][512] bf16, n-major (N x K)
    unsigned short* __restrict__ C,         // [Mvalid][512] bf16
    int Mvalid)
{
  __shared__ unsigned short As[128 * 64];   // 16 KB
  __shared__ unsigned short Bs[128 * 64];   // 16 KB

  // bijective XCD swizzle (m204): nwg = gridDim.x, 8 XCDs
  int nwg  = gridDim.x;
  int orig = blockIdx.x;
  int q = nwg >> 3, r = nwg & 7;
  int xcd = orig & 7, xpos = orig >> 3;
  int wgid = (xcd < r ? xcd * (q + 1) : r * (q + 1) + (xcd - r) * q) + xpos;
  int bcol = (wgid & 3) * 128;              // N/128 = 4, fastest
  int brow = (wgid >> 2) * 128;

  int tid  = threadIdx.x;
  int lane = tid & 63;
  int wave = tid >> 6;
  int wr = wave >> 1, wc = wave & 1;        // 2x2 waves -> 64x64 each
  int r16 = lane & 15;
  int kl16 = (lane >> 4) * 16;              // byte offset of this lane-group's k8

  const f32x4 zero = {0.f, 0.f, 0.f, 0.f};
  f32x4 acc[4][4];
  #pragma unroll
  for (int m = 0; m < 4; ++m)
    #pragma unroll
    for (int n = 0; n < 4; ++n) acc[m][n] = zero;

  for (int kt = 0; kt < 512; kt += 64) {
    #pragma unroll
    for (int i = 0; i < 4; ++i) {
      int c   = tid + (i << 8);             // 0..1023
      int row = c >> 3;                     // 0..127
      int qo  = ((c & 7) << 4) ^ ((row & 7) << 4);   // logical byte col in [0,128)
      gload_lds16(A + (size_t)(brow + row) * 512 + kt + (qo >> 1),
                  (char*)As + (size_t)c * 16);
      gload_lds16(B + (size_t)(bcol + row) * 512 + kt + (qo >> 1),
                  (char*)Bs + (size_t)c * 16);
    }
    __syncthreads();

    #pragma unroll
    for (int ks = 0; ks < 2; ++ks) {
      short8 af[4], bfr[4];
      int qo = kl16 + ks * 64;              // logical byte col of fragment
      #pragma unroll
      for (int m = 0; m < 4; ++m) {
        int row = wr * 64 + m * 16 + r16;
        af[m] = *(const short8*)((const char*)As + row * 128 + (qo ^ ((row & 7) << 4)));
      }
      #pragma unroll
      for (int n = 0; n < 4; ++n) {
        int row = wc * 64 + n * 16 + r16;
        bfr[n] = *(const short8*)((const char*)Bs + row * 128 + (qo ^ ((row & 7) << 4)));
      }
      #pragma unroll
      for (int m = 0; m < 4; ++m)
        #pragma unroll
        for (int n = 0; n < 4; ++n)
          acc[m][n] = __builtin_amdgcn_mfma_f32_16x16x32_bf16(af[m], bfr[n], acc[m][n], 0, 0, 0);
    }
    __syncthreads();
  }

  int rbase = (lane >> 4) * 4;   // C/D: col=lane&15, row=(lane>>4)*4+reg
  int ccol  = lane & 15;
  #pragma unroll
  for (int m = 0; m < 4; ++m)
    #pragma unroll
    for (int n = 0; n < 4; ++n)
      #pragma unroll
      for (int i = 0; i < 4; ++i) {
        int grow = brow + wr * 64 + m * 16 + rbase + i;
        if (grow < Mvalid) {
          int gcol = bcol + wc * 64 + n * 16 + ccol;
          C[(size_t)grow * 512 + gcol] = f2bf(acc[m][n][i]);
        }
      }
}

// ---------------- aggregation: out[i] = b + dis_i^2*h[i] + sum_e c_e*h[s_e] ----
// one wave per node; lane owns dims [lane*8, lane*8+8). Edge coefficient is
// precomputed (k_epre): per edge, ONE uniform 8B pair load -> row gather
// (2-deep chain, was 3-deep). 4/2/1 unroll ladder for gather MLP.
__global__ __launch_bounds__(256) void k_agg(
    const unsigned short* __restrict__ h, const float* __restrict__ dis,
    const float* __restrict__ bias, const int* __restrict__ rowstart,
    const int2* __restrict__ ep, void* __restrict__ outp, int outBf16)
{
  int node = blockIdx.x * 4 + (threadIdx.x >> 6);
  int lane = threadIdx.x & 63;
  if (node >= NN) return;                  // xb pad rows stay zero from k_prep
  const uint4* hp = (const uint4*)h;
  const float4* bp = (const float4*)bias;
  float4 b0 = bp[lane * 2], b1 = bp[lane * 2 + 1];   // hoisted (independent)
  float di = dis[node];
  int p0 = rowstart[node], p1 = rowstart[node + 1];
  uint4 hv = hp[(size_t)node * 64 + lane];
  float t0[8], t1[8], t2[8], t3[8], acc[8];
  unpack8(hv, t0);
  float selfc = di * di;                   // self-loop: dis_i * 1 * dis_i
  #pragma unroll
  for (int j = 0; j < 8; ++j) acc[j] = t0[j] * selfc;
  int p = p0;
  for (; p + 4 <= p1; p += 4) {
    int2 e0 = ep[p], e1v = ep[p + 1], e2v = ep[p + 2], e3v = ep[p + 3];
    uint4 v0 = hp[(size_t)e0.x  * 64 + lane];
    uint4 v1 = hp[(size_t)e1v.x * 64 + lane];
    uint4 v2 = hp[(size_t)e2v.x * 64 + lane];
    uint4 v3 = hp[(size_t)e3v.x * 64 + lane];
    float c0 = __int_as_float(e0.y)  * di;
    float c1 = __int_as_float(e1v.y) * di;
    float c2 = __int_as_float(e2v.y) * di;
    float c3 = __int_as_float(e3v.y) * di;
    unpack8(v0, t0); unpack8(v1, t1); unpack8(v2, t2); unpack8(v3, t3);
    #pragma unroll
    for (int j = 0; j < 8; ++j) acc[j] += c0 * t0[j];
    #pragma unroll
    for (int j = 0; j < 8; ++j) acc[j] += c1 * t1[j];
    #pragma unroll
    for (int j = 0; j < 8; ++j) acc[j] += c2 * t2[j];
    #pragma unroll
    for (int j = 0; j < 8; ++j) acc[j] += c3 * t3[j];
  }
  for (; p + 2 <= p1; p += 2) {
    int2 e0 = ep[p], e1v = ep[p + 1];
    uint4 v0 = hp[(size_t)e0.x  * 64 + lane];
    uint4 v1 = hp[(size_t)e1v.x * 64 + lane];
    float c0 = __int_as_float(e0.y)  * di;
    float c1 = __int_as_float(e1v.y) * di;
    unpack8(v0, t0); unpack8(v1, t1);
    #pragma unroll
    for (int j = 0; j < 8; ++j) acc[j] += c0 * t0[j];
    #pragma unroll
    for (int j = 0; j < 8; ++j) acc[j] += c1 * t1[j];
  }
  if (p < p1) {
    int2 e0 = ep[p];
    uint4 v0 = hp[(size_t)e0.x * 64 + lane];
    float c0 = __int_as_float(e0.y) * di;
    unpack8(v0, t0);
    #pragma unroll
    for (int j = 0; j < 8; ++j) acc[j] += c0 * t0[j];
  }
  acc[0] += b0.x; acc[1] += b0.y; acc[2] += b0.z; acc[3] += b0.w;
  acc[4] += b1.x; acc[5] += b1.y; acc[6] += b1.z; acc[7] += b1.w;
  if (outBf16) {                           // layer 1: fuse ReLU + bf16 cast
    ushort8 o;
    #pragma unroll
    for (int j = 0; j < 8; ++j) o[j] = f2bf(fmaxf(acc[j], 0.0f));
    *(ushort8*)((unsigned short*)outp + (size_t)node * 512 + lane * 8) = o;
  } else {                                 // layer 2: f32 final output
    // nontemporal: write-once, never re-read -> keep L2 clean for h gathers
    // (use clang ext-vector f32x4 -- HIP float4 is a class and is rejected
    //  by __builtin_nontemporal_store)
    float* op = (float*)outp + (size_t)node * 512 + lane * 8;
    f32x4 o0 = {acc[0], acc[1], acc[2], acc[3]};
    f32x4 o1 = {acc[4], acc[5], acc[6], acc[7]};
    __builtin_nontemporal_store(o0, (f32x4*)op);
    __builtin_nontemporal_store(o1, (f32x4*)(op + 4));
  }
}

// ---------------- workspace layout ----------------
constexpr size_t al(size_t x) { return (x + 255) & ~(size_t)255; }
constexpr size_t SZ_XB  = (size_t)MPAD * DDIM * 2;   // bf16 x (padded); reused as relu(h1)
constexpr size_t SZ_H   = (size_t)NN   * DDIM * 2;   // bf16 h1; reused as h2
constexpr size_t SZ_WT  = (size_t)DDIM * DDIM * 2;
constexpr size_t O_XB   = 0;
constexpr size_t O_H    = al(O_XB + SZ_XB);
constexpr size_t O_WT1  = al(O_H + SZ_H);
constexpr size_t O_WT2  = al(O_WT1 + SZ_WT);
constexpr size_t O_DIS1 = al(O_WT2 + SZ_WT);
constexpr size_t O_DIS2 = al(O_DIS1 + (size_t)NN * 4);
constexpr size_t O_CNT  = al(O_DIS2 + (size_t)NN * 4);
constexpr size_t O_RS   = al(O_CNT + (size_t)NN * 4);
constexpr size_t O_POS  = al(O_RS + (size_t)(NN + 1) * 4);
constexpr size_t O_CSRE = al(O_POS + (size_t)NE * 4);
constexpr size_t O_E1   = al(O_CSRE + (size_t)NE * 8);
constexpr size_t O_E2   = al(O_E1 + (size_t)NE * 8);
constexpr size_t O_BSUM = al(O_E2 + (size_t)NE * 8);
constexpr size_t O_BOFF = al(O_BSUM + (size_t)NB_SCAN * 4);
constexpr size_t WS_NEED = al(O_BOFF + (size_t)NB_SCAN * 4);

extern "C" void kernel_launch(void* const* d_in, const int* in_sizes, int n_in,
                              void* d_out, int out_size, void* d_ws, size_t ws_size,
                              hipStream_t stream) {
  const float* x  = (const float*)d_in[0];
  const int*   ei = (const int*)d_in[1];
  const float* ea = (const float*)d_in[2];
  const float* W1 = (const float*)d_in[3];
  const float* b1 = (const float*)d_in[4];
  const float* W2 = (const float*)d_in[5];
  const float* b2 = (const float*)d_in[6];
  if (ws_size < WS_NEED) return;

  char* ws = (char*)d_ws;
  unsigned short* xb   = (unsigned short*)(ws + O_XB);   // also relu(h1) later
  unsigned short* h    = (unsigned short*)(ws + O_H);    // h1, then h2
  unsigned short* Wt1  = (unsigned short*)(ws + O_WT1);
  unsigned short* Wt2  = (unsigned short*)(ws + O_WT2);
  float* dis1 = (float*)(ws + O_DIS1);
  float* dis2 = (float*)(ws + O_DIS2);
  int*   cnt  = (int*)(ws + O_CNT);
  int*   rs   = (int*)(ws + O_RS);
  int*   pos  = (int*)(ws + O_POS);
  int2*  csre = (int2*)(ws + O_CSRE);
  int2*  e1   = (int2*)(ws + O_E1);
  int2*  e2   = (int2*)(ws + O_E2);
  int*   bsum = (int*)(ws + O_BSUM);
  int*   boff = (int*)(ws + O_BOFF);

  // fused conversions + counter init
  k_prep <<<2048, 256, 0, stream>>>(x, W1, W2, xb, Wt1, Wt2, cnt);
  // graph build (proven 3-kernel scan) + edge-coefficient precompute
  k_deg  <<<(NE + 255) / 256, 256, 0, stream>>>(ei, cnt, pos);
  k_scan1<<<NB_SCAN, 256, 0, stream>>>(cnt, bsum);
  k_scan2<<<1, 256, 0, stream>>>(bsum, boff, rs);
  k_scan3<<<NB_SCAN, 256, 0, stream>>>(cnt, boff, rs);
  k_fill <<<(NE + 255) / 256, 256, 0, stream>>>(ei, ea, rs, pos, csre);
  k_dis  <<<NB_SCAN, 256, 0, stream>>>(rs, csre, dis1, dis2);
  k_epre <<<(NE + 255) / 256, 256, 0, stream>>>(csre, dis1, dis2, e1, e2);

  int ngemm = (MPAD / 128) * (DDIM / 128);   // 1564
  // layer 1
  k_gemm<<<ngemm, 256, 0, stream>>>(xb, Wt1, h, NN);
  k_agg <<<(NN + 3) / 4, 256, 0, stream>>>(h, dis1, b1, rs, e1,
                                           (void*)xb, 1);        // relu->bf16 into xb
  // layer 2
  k_gemm<<<ngemm, 256, 0, stream>>>(xb, Wt2, h, NN);
  k_agg <<<(NN + 3) / 4, 256, 0, stream>>>(h, dis2, b2, rs, e2,
                                           d_out, 0);            // f32 final
}

// Round 13
// 219.806 us; speedup vs baseline: 1.4344x; 1.0052x over previous
//
#include <hip/hip_runtime.h>
#include <hip/hip_bf16.h>

#define NN   50000
#define NE   160000
#define DDIM 512
#define MPAD 50176          // 196 * 256
#define NB_SCAN 196         // ceil(NN/256)

typedef __attribute__((ext_vector_type(8))) short  short8;
typedef __attribute__((ext_vector_type(8))) unsigned short ushort8;
typedef __attribute__((ext_vector_type(4))) float  f32x4;

__device__ __forceinline__ unsigned short f2bf(float f) {
  union { float f; unsigned u; } v; v.f = f;
  unsigned u = v.u;
  unsigned r = (u + 0x7FFFu + ((u >> 16) & 1u)) >> 16;   // RNE
  return (unsigned short)r;
}
__device__ __forceinline__ float bf2f(unsigned short s) {
  union { unsigned u; float f; } v; v.u = ((unsigned)s) << 16;
  return v.f;
}
__device__ __forceinline__ void unpack8(uint4 v, float* t) {
  t[0] = bf2f(v.x & 0xffff); t[1] = bf2f(v.x >> 16);
  t[2] = bf2f(v.y & 0xffff); t[3] = bf2f(v.y >> 16);
  t[4] = bf2f(v.z & 0xffff); t[5] = bf2f(v.z >> 16);
  t[6] = bf2f(v.w & 0xffff); t[7] = bf2f(v.w >> 16);
}
__device__ __forceinline__ void gload_lds16(const void* g, void* l) {
  __builtin_amdgcn_global_load_lds(
      (const __attribute__((address_space(1))) unsigned int*)g,
      (__attribute__((address_space(3))) unsigned int*)l, 16, 0, 0);
}

// ---------------- fused prep: cvt_x + cvt_w (both) + cnt zero ----------------
__global__ __launch_bounds__(256) void k_prep(
    const float* __restrict__ x, const float* __restrict__ W1,
    const float* __restrict__ W2, unsigned short* __restrict__ xb,
    unsigned short* __restrict__ Wt1, unsigned short* __restrict__ Wt2,
    int* __restrict__ cnt)
{
  int stride = gridDim.x * 256;
  int g0 = blockIdx.x * 256 + threadIdx.x;
  for (size_t t = g0; t < (size_t)MPAD * 64; t += stride) {
    ushort8 o;
    if (t * 8 < (size_t)NN * DDIM) {
      const float4* xp = (const float4*)x;
      float4 a = xp[t * 2], b = xp[t * 2 + 1];
      o[0] = f2bf(a.x); o[1] = f2bf(a.y); o[2] = f2bf(a.z); o[3] = f2bf(a.w);
      o[4] = f2bf(b.x); o[5] = f2bf(b.y); o[6] = f2bf(b.z); o[7] = f2bf(b.w);
    } else {
      #pragma unroll
      for (int j = 0; j < 8; ++j) o[j] = 0;
    }
    *(ushort8*)(xb + t * 8) = o;
  }
  for (int t = g0; t < DDIM * DDIM; t += stride) {
    int k = t >> 9, n = t & 511;
    Wt1[n * 512 + k] = f2bf(W1[t]);
    Wt2[n * 512 + k] = f2bf(W2[t]);
  }
  for (int i = g0; i < NN; i += stride) cnt[i] = 0;
}

// ---------------- graph build ----------------
__global__ void k_deg(const int* __restrict__ ei, int* __restrict__ cnt,
                      int* __restrict__ pos) {
  int e = blockIdx.x * 256 + threadIdx.x;
  if (e < NE) {
    int d = ei[NE + e];
    pos[e] = atomicAdd(&cnt[d], 1);
  }
}

__global__ void k_scan1(const int* __restrict__ cnt, int* __restrict__ bsum) {
  __shared__ int sd[256];
  int t = threadIdx.x;
  int i = blockIdx.x * 256 + t;
  sd[t] = (i < NN) ? cnt[i] : 0;
  __syncthreads();
  for (int off = 128; off > 0; off >>= 1) {
    if (t < off) sd[t] += sd[t + off];
    __syncthreads();
  }
  if (t == 0) bsum[blockIdx.x] = sd[0];
}

__global__ void k_scan2(const int* __restrict__ bsum, int* __restrict__ boff,
                        int* __restrict__ rowstart) {
  __shared__ int sd[256];
  int t = threadIdx.x;
  int v = (t < NB_SCAN) ? bsum[t] : 0;
  int x = v;
  sd[t] = x;
  __syncthreads();
  for (int off = 1; off < 256; off <<= 1) {
    int u = (t >= off) ? sd[t - off] : 0;
    __syncthreads();
    x += u; sd[t] = x;
    __syncthreads();
  }
  if (t < NB_SCAN) boff[t] = x - v;
  if (t == 0) rowstart[NN] = NE;
}

__global__ void k_scan3(const int* __restrict__ cnt, const int* __restrict__ boff,
                        int* __restrict__ rowstart) {
  __shared__ int sd[256];
  int t = threadIdx.x;
  int i = blockIdx.x * 256 + t;
  int v = (i < NN) ? cnt[i] : 0;
  int x = v;
  sd[t] = x;
  __syncthreads();
  for (int off = 1; off < 256; off <<= 1) {
    int u = (t >= off) ? sd[t - off] : 0;
    __syncthreads();
    x += u; sd[t] = x;
    __syncthreads();
  }
  if (i < NN) rowstart[i] = boff[blockIdx.x] + x - v;
}

__global__ void k_fill(const int* __restrict__ ei, const float* __restrict__ ea,
                       const int* __restrict__ rowstart, const int* __restrict__ pos,
                       int2* __restrict__ csre) {
  int e = blockIdx.x * 256 + threadIdx.x;
  if (e < NE) {
    int d = ei[NE + e];
    int p = rowstart[d] + pos[e];
    csre[p] = make_int2(ei[e], __float_as_int(ea[e]));
  }
}

__global__ void k_dis(const int* __restrict__ rowstart, const int2* __restrict__ csre,
                      float* __restrict__ dis1, float* __restrict__ dis2) {
  int i = blockIdx.x * 256 + threadIdx.x;
  if (i < NN) {
    int p0 = rowstart[i], p1 = rowstart[i + 1];
    float s = 1.0f;
    for (int p = p0; p < p1; ++p) s += __int_as_float(csre[p].y);
    dis1[i] = rsqrtf(s);
    dis2[i] = rsqrtf(1.0f + (float)(p1 - p0));
  }
}

__global__ void k_epre(const int2* __restrict__ csre, const float* __restrict__ dis1,
                       const float* __restrict__ dis2, int2* __restrict__ e1,
                       int2* __restrict__ e2) {
  int e = blockIdx.x * 256 + threadIdx.x;
  if (e < NE) {
    int2 pr = csre[e];
    int s = pr.x;
    float w = __int_as_float(pr.y);
    e1[e] = make_int2(s, __float_as_int(w * dis1[s]));
    e2[e] = make_int2(s, __float_as_int(dis2[s]));
  }
}

// ---------------- GEMM: 8-phase 256x256 (m201 template port) ----------------
// BM=BN=256, BK=64, 512 thr = 8 waves (2M x 4N), wave tile 128x64.
// LDS: 2 dbuf x 2 half x 128x64 x {A,B} = 128 KB. Per K-tile, 4 phases
// (C-quadrants, 16 MFMA each); ds_reads = minimum 24/wave/tile via
// register-held subtiles (A-half live P1->P4, B all-n live P1->P4).
// Stage placement from consumption proofs: B halves consumed P2-end -> staged
// P3; A halves consumed P3-end -> staged P4 (tile kt+2, same dbuf slot).
// vmcnt(8) ONCE per tile at P4 (8 = kt's own stages; everything older drained
// => tile kt+1 certified). Never vmcnt(0) in-loop. R2-proven XOR swizzle
// (128B rows). Bijective XCD chunking (392 % 8 == 0).
__global__ __launch_bounds__(512, 2) void k_gemm(
    const unsigned short* __restrict__ A,   // [MPAD][512] bf16 row-major
    const unsigned short* __restrict__ B,   // [512][512] bf16, n-major
    unsigned short* __restrict__ C,         // [Mvalid][512] bf16
    int Mvalid)
{
  __shared__ unsigned short Ah[2][2][128 * 64];   // [dbuf][half] 16 KB each
  __shared__ unsigned short Bh[2][2][128 * 64];

  int nwg  = gridDim.x;                     // 392, divisible by 8
  int orig = blockIdx.x;
  int wgid = (orig & 7) * (nwg >> 3) + (orig >> 3);
  int bcol = (wgid & 1) * 256;              // N/256 = 2, fastest
  int brow = (wgid >> 1) * 256;

  int tid  = threadIdx.x;
  int lane = tid & 63;
  int wave = tid >> 6;
  int wr = wave >> 2, wc = wave & 3;        // 2M x 4N
  int r16 = lane & 15;
  int kl16 = (lane >> 4) * 16;

  const f32x4 zero = {0.f, 0.f, 0.f, 0.f};
  f32x4 acc[8][4];
  #pragma unroll
  for (int m = 0; m < 8; ++m)
    #pragma unroll
    for (int n = 0; n < 4; ++n) acc[m][n] = zero;

  // stage one 16KB half (1024 x 16B chunks, 2/thread). linear LDS dest,
  // inverse-swizzled global source (rule-21).
#define STAGE_HALF(XX, gbase, d, h, kt)                                         \
  { _Pragma("unroll")                                                           \
    for (int i = 0; i < 2; ++i) {                                               \
      int c   = tid + (i << 9);                                                 \
      int row = c >> 3;                                                         \
      int sc  = (c & 7) ^ (row & 7);                                            \
      gload_lds16((gbase) + (size_t)row * 512 + (kt) * 64 + sc * 8,             \
                  (char*)XX[d][h] + (size_t)c * 16); } }

  // fragment reads (swizzled): A half = wr, row-in-half = m*16+r16;
  // B half = wc>>1, row-in-half = (wc&1)*64 + n*16 + r16.
#define LDA(d, m, ks)                                                           \
  (*(const short8*)((const char*)Ah[d][wr] + ((m) * 16 + r16) * 128 +           \
    ((kl16 + (ks) * 64) ^ ((r16 & 7) << 4))))
#define LDB(d, n, ks)                                                           \
  (*(const short8*)((const char*)Bh[d][wc >> 1] +                               \
    (((wc & 1) * 64 + (n) * 16 + r16) * 128) +                                  \
    ((kl16 + (ks) * 64) ^ ((r16 & 7) << 4))))

#define BARF() { asm volatile("" ::: "memory"); __builtin_amdgcn_s_barrier();   \
                 asm volatile("" ::: "memory"); __builtin_amdgcn_sched_barrier(0); }
#define LGK0() { asm volatile("s_waitcnt lgkmcnt(0)" ::: "memory");             \
                 __builtin_amdgcn_sched_barrier(0); }

  const unsigned short* Ab0 = A + (size_t)brow * 512;
  const unsigned short* Ab1 = A + (size_t)(brow + 128) * 512;
  const unsigned short* Bb0 = B + (size_t)bcol * 512;
  const unsigned short* Bb1 = B + (size_t)(bcol + 128) * 512;

  // prologue: stage tiles 0 and 1 fully (FIFO: tile 0 first)
  STAGE_HALF(Ah, Ab0, 0, 0, 0); STAGE_HALF(Ah, Ab1, 0, 1, 0);
  STAGE_HALF(Bh, Bb0, 0, 0, 0); STAGE_HALF(Bh, Bb1, 0, 1, 0);
  STAGE_HALF(Ah, Ab0, 1, 0, 1); STAGE_HALF(Ah, Ab1, 1, 1, 1);
  STAGE_HALF(Bh, Bb0, 1, 0, 1); STAGE_HALF(Bh, Bb1, 1, 1, 1);
  asm volatile("s_waitcnt vmcnt(8)" ::: "memory");   // tile 0 landed
  BARF();

  #pragma unroll
  for (int kt = 0; kt < 8; ++kt) {
    const int d = kt & 1;
    short8 af[8][2], bf[4][2];

    // ---- P1: read A-half(wr) m0-3 + B n0-1; MFMA quad (m0-3 x n0-1) ----
    #pragma unroll
    for (int m = 0; m < 4; ++m) { af[m][0] = LDA(d, m, 0); af[m][1] = LDA(d, m, 1); }
    #pragma unroll
    for (int n = 0; n < 2; ++n) { bf[n][0] = LDB(d, n, 0); bf[n][1] = LDB(d, n, 1); }
    BARF(); LGK0();
    __builtin_amdgcn_s_setprio(1);
    #pragma unroll
    for (int ks = 0; ks < 2; ++ks)
      #pragma unroll
      for (int m = 0; m < 4; ++m)
        #pragma unroll
        for (int n = 0; n < 2; ++n)
          acc[m][n] = __builtin_amdgcn_mfma_f32_16x16x32_bf16(af[m][ks], bf[n][ks], acc[m][n], 0, 0, 0);
    __builtin_amdgcn_s_setprio(0);
    BARF();

    // ---- P2: read B n2-3; MFMA quad (m0-3 x n2-3) ----
    #pragma unroll
    for (int n = 2; n < 4; ++n) { bf[n][0] = LDB(d, n, 0); bf[n][1] = LDB(d, n, 1); }
    BARF(); LGK0();
    __builtin_amdgcn_s_setprio(1);
    #pragma unroll
    for (int ks = 0; ks < 2; ++ks)
      #pragma unroll
      for (int m = 0; m < 4; ++m)
        #pragma unroll
        for (int n = 2; n < 4; ++n)
          acc[m][n] = __builtin_amdgcn_mfma_f32_16x16x32_bf16(af[m][ks], bf[n][ks], acc[m][n], 0, 0, 0);
    __builtin_amdgcn_s_setprio(0);
    BARF();

    // ---- P3: read A m4-7; stage B halves of tile kt+2 (B slot consumed
    //          P2-end, certified by P2's post-barrier); MFMA (m4-7 x n2-3) ----
    #pragma unroll
    for (int m = 4; m < 8; ++m) { af[m][0] = LDA(d, m, 0); af[m][1] = LDA(d, m, 1); }
    if (kt < 6) { STAGE_HALF(Bh, Bb0, d, 0, kt + 2); STAGE_HALF(Bh, Bb1, d, 1, kt + 2); }
    BARF(); LGK0();
    __builtin_amdgcn_s_setprio(1);
    #pragma unroll
    for (int ks = 0; ks < 2; ++ks)
      #pragma unroll
      for (int m = 4; m < 8; ++m)
        #pragma unroll
        for (int n = 2; n < 4; ++n)
          acc[m][n] = __builtin_amdgcn_mfma_f32_16x16x32_bf16(af[m][ks], bf[n][ks], acc[m][n], 0, 0, 0);
    __builtin_amdgcn_s_setprio(0);
    BARF();

    // ---- P4: stage A halves of tile kt+2 (A consumed P3-end); MFMA
    //          (m4-7 x n0-1, B n0-1 held since P1); counted vmcnt ----
    if (kt < 6) { STAGE_HALF(Ah, Ab0, d, 0, kt + 2); STAGE_HALF(Ah, Ab1, d, 1, kt + 2); }
    BARF();
    __builtin_amdgcn_s_setprio(1);
    #pragma unroll
    for (int ks = 0; ks < 2; ++ks)
      #pragma unroll
      for (int m = 4; m < 8; ++m)
        #pragma unroll
        for (int n = 0; n < 2; ++n)
          acc[m][n] = __builtin_amdgcn_mfma_f32_16x16x32_bf16(af[m][ks], bf[n][ks], acc[m][n], 0, 0, 0);
    __builtin_amdgcn_s_setprio(0);
    if (kt <= 5)      asm volatile("s_waitcnt vmcnt(8)" ::: "memory");  // tile kt+1 certified
    else if (kt == 6) asm volatile("s_waitcnt vmcnt(0)" ::: "memory");  // tile 7 certified
    BARF();
  }
#undef STAGE_HALF
#undef LDA
#undef LDB
#undef BARF
#undef LGK0

  int rbase = (lane >> 4) * 4;   // C/D: col=lane&15, row=(lane>>4)*4+reg
  int ccol  = lane & 15;
  #pragma unroll
  for (int m = 0; m < 8; ++m)
    #pragma unroll
    for (int n = 0; n < 4; ++n)
      #pragma unroll
      for (int i = 0; i < 4; ++i) {
        int grow = brow + wr * 128 + m * 16 + rbase + i;
        if (grow < Mvalid) {
          int gcol = bcol + wc * 64 + n * 16 + ccol;
          C[(size_t)grow * 512 + gcol] = f2bf(acc[m][n][i]);
        }
      }
}

// ---------------- aggregation: out[i] = b + dis_i^2*h[i] + sum_e c_e*h[s_e] ----
__global__ __launch_bounds__(256) void k_agg(
    const unsigned short* __restrict__ h, const float* __restrict__ dis,
    const float* __restrict__ bias, const int* __restrict__ rowstart,
    const int2* __restrict__ ep, void* __restrict__ outp, int outBf16)
{
  int node = blockIdx.x * 4 + (threadIdx.x >> 6);
  int lane = threadIdx.x & 63;
  if (node >= NN) return;                  // xb pad rows stay zero from k_prep
  const uint4* hp = (const uint4*)h;
  const float4* bp = (const float4*)bias;
  float4 b0 = bp[lane * 2], b1 = bp[lane * 2 + 1];
  float di = dis[node];
  int p0 = rowstart[node], p1 = rowstart[node + 1];
  uint4 hv = hp[(size_t)node * 64 + lane];
  float t0[8], t1[8], t2[8], t3[8], acc[8];
  unpack8(hv, t0);
  float selfc = di * di;
  #pragma unroll
  for (int j = 0; j < 8; ++j) acc[j] = t0[j] * selfc;
  int p = p0;
  for (; p + 4 <= p1; p += 4) {
    int2 e0 = ep[p], e1v = ep[p + 1], e2v = ep[p + 2], e3v = ep[p + 3];
    uint4 v0 = hp[(size_t)e0.x  * 64 + lane];
    uint4 v1 = hp[(size_t)e1v.x * 64 + lane];
    uint4 v2 = hp[(size_t)e2v.x * 64 + lane];
    uint4 v3 = hp[(size_t)e3v.x * 64 + lane];
    float c0 = __int_as_float(e0.y)  * di;
    float c1 = __int_as_float(e1v.y) * di;
    float c2 = __int_as_float(e2v.y) * di;
    float c3 = __int_as_float(e3v.y) * di;
    unpack8(v0, t0); unpack8(v1, t1); unpack8(v2, t2); unpack8(v3, t3);
    #pragma unroll
    for (int j = 0; j < 8; ++j) acc[j] += c0 * t0[j];
    #pragma unroll
    for (int j = 0; j < 8; ++j) acc[j] += c1 * t1[j];
    #pragma unroll
    for (int j = 0; j < 8; ++j) acc[j] += c2 * t2[j];
    #pragma unroll
    for (int j = 0; j < 8; ++j) acc[j] += c3 * t3[j];
  }
  for (; p + 2 <= p1; p += 2) {
    int2 e0 = ep[p], e1v = ep[p + 1];
    uint4 v0 = hp[(size_t)e0.x  * 64 + lane];
    uint4 v1 = hp[(size_t)e1v.x * 64 + lane];
    float c0 = __int_as_float(e0.y)  * di;
    float c1 = __int_as_float(e1v.y) * di;
    unpack8(v0, t0); unpack8(v1, t1);
    #pragma unroll
    for (int j = 0; j < 8; ++j) acc[j] += c0 * t0[j];
    #pragma unroll
    for (int j = 0; j < 8; ++j) acc[j] += c1 * t1[j];
  }
  if (p < p1) {
    int2 e0 = ep[p];
    uint4 v0 = hp[(size_t)e0.x * 64 + lane];
    float c0 = __int_as_float(e0.y) * di;
    unpack8(v0, t0);
    #pragma unroll
    for (int j = 0; j < 8; ++j) acc[j] += c0 * t0[j];
  }
  acc[0] += b0.x; acc[1] += b0.y; acc[2] += b0.z; acc[3] += b0.w;
  acc[4] += b1.x; acc[5] += b1.y; acc[6] += b1.z; acc[7] += b1.w;
  if (outBf16) {
    ushort8 o;
    #pragma unroll
    for (int j = 0; j < 8; ++j) o[j] = f2bf(fmaxf(acc[j], 0.0f));
    *(ushort8*)((unsigned short*)outp + (size_t)node * 512 + lane * 8) = o;
  } else {
    float* op = (float*)outp + (size_t)node * 512 + lane * 8;
    f32x4 o0 = {acc[0], acc[1], acc[2], acc[3]};
    f32x4 o1 = {acc[4], acc[5], acc[6], acc[7]};
    __builtin_nontemporal_store(o0, (f32x4*)op);
    __builtin_nontemporal_store(o1, (f32x4*)(op + 4));
  }
}

// ---------------- workspace layout ----------------
constexpr size_t al(size_t x) { return (x + 255) & ~(size_t)255; }
constexpr size_t SZ_XB  = (size_t)MPAD * DDIM * 2;
constexpr size_t SZ_H   = (size_t)NN   * DDIM * 2;
constexpr size_t SZ_WT  = (size_t)DDIM * DDIM * 2;
constexpr size_t O_XB   = 0;
constexpr size_t O_H    = al(O_XB + SZ_XB);
constexpr size_t O_WT1  = al(O_H + SZ_H);
constexpr size_t O_WT2  = al(O_WT1 + SZ_WT);
constexpr size_t O_DIS1 = al(O_WT2 + SZ_WT);
constexpr size_t O_DIS2 = al(O_DIS1 + (size_t)NN * 4);
constexpr size_t O_CNT  = al(O_DIS2 + (size_t)NN * 4);
constexpr size_t O_RS   = al(O_CNT + (size_t)NN * 4);
constexpr size_t O_POS  = al(O_RS + (size_t)(NN + 1) * 4);
constexpr size_t O_CSRE = al(O_POS + (size_t)NE * 4);
constexpr size_t O_E1   = al(O_CSRE + (size_t)NE * 8);
constexpr size_t O_E2   = al(O_E1 + (size_t)NE * 8);
constexpr size_t O_BSUM = al(O_E2 + (size_t)NE * 8);
constexpr size_t O_BOFF = al(O_BSUM + (size_t)NB_SCAN * 4);
constexpr size_t WS_NEED = al(O_BOFF + (size_t)NB_SCAN * 4);

extern "C" void kernel_launch(void* const* d_in, const int* in_sizes, int n_in,
                              void* d_out, int out_size, void* d_ws, size_t ws_size,
                              hipStream_t stream) {
  const float* x  = (const float*)d_in[0];
  const int*   ei = (const int*)d_in[1];
  const float* ea = (const float*)d_in[2];
  const float* W1 = (const float*)d_in[3];
  const float* b1 = (const float*)d_in[4];
  const float* W2 = (const float*)d_in[5];
  const float* b2 = (const float*)d_in[6];
  if (ws_size < WS_NEED) return;

  char* ws = (char*)d_ws;
  unsigned short* xb   = (unsigned short*)(ws + O_XB);
  unsigned short* h    = (unsigned short*)(ws + O_H);
  unsigned short* Wt1  = (unsigned short*)(ws + O_WT1);
  unsigned short* Wt2  = (unsigned short*)(ws + O_WT2);
  float* dis1 = (float*)(ws + O_DIS1);
  float* dis2 = (float*)(ws + O_DIS2);
  int*   cnt  = (int*)(ws + O_CNT);
  int*   rs   = (int*)(ws + O_RS);
  int*   pos  = (int*)(ws + O_POS);
  int2*  csre = (int2*)(ws + O_CSRE);
  int2*  e1   = (int2*)(ws + O_E1);
  int2*  e2   = (int2*)(ws + O_E2);
  int*   bsum = (int*)(ws + O_BSUM);
  int*   boff = (int*)(ws + O_BOFF);

  k_prep <<<2048, 256, 0, stream>>>(x, W1, W2, xb, Wt1, Wt2, cnt);
  k_deg  <<<(NE + 255) / 256, 256, 0, stream>>>(ei, cnt, pos);
  k_scan1<<<NB_SCAN, 256, 0, stream>>>(cnt, bsum);
  k_scan2<<<1, 256, 0, stream>>>(bsum, boff, rs);
  k_scan3<<<NB_SCAN, 256, 0, stream>>>(cnt, boff, rs);
  k_fill <<<(NE + 255) / 256, 256, 0, stream>>>(ei, ea, rs, pos, csre);
  k_dis  <<<NB_SCAN, 256, 0, stream>>>(rs, csre, dis1, dis2);
  k_epre <<<(NE + 255) / 256, 256, 0, stream>>>(csre, dis1, dis2, e1, e2);

  int ngemm = (MPAD / 256) * (DDIM / 256);   // 392
  // layer 1
  k_gemm<<<ngemm, 512, 0, stream>>>(xb, Wt1, h, NN);
  k_agg <<<(NN + 3) / 4, 256, 0, stream>>>(h, dis1, b1, rs, e1,
                                           (void*)xb, 1);        // relu->bf16 into xb
  // layer 2
  k_gemm<<<ngemm, 512, 0, stream>>>(xb, Wt2, h, NN);
  k_agg <<<(NN + 3) / 4, 256, 0, stream>>>(h, dis2, b2, rs, e2,
                                           d_out, 0);            // f32 final
}